// Round 2
// baseline (368.312 us; speedup 1.0000x reference)
//
#include <hip/hip_runtime.h>
#include <hip/hip_fp16.h>
#include <math.h>

#define HW 65536               // 256*256
#define PITCH 272              // padded fp16 conv plane: 7+256+9 cols
#define PLANE (PITCH * PITCH)  // 73984 fp16 elements per (b,c,i) plane

typedef float v2f __attribute__((ext_vector_type(2), aligned(8)));
typedef _Float16 h2 __attribute__((ext_vector_type(2)));

__device__ __forceinline__ h2 uh(unsigned u) { return __builtin_bit_cast(h2, u); }

#define CEH(a, b) { h2 _t = __builtin_elementwise_min(a, b); \
                    b = __builtin_elementwise_max(a, b); a = _t; }

__device__ __forceinline__ void sort8_h2(h2* v) {
    CEH(v[0], v[1]); CEH(v[2], v[3]); CEH(v[4], v[5]); CEH(v[6], v[7]);
    CEH(v[0], v[2]); CEH(v[1], v[3]); CEH(v[4], v[6]); CEH(v[5], v[7]);
    CEH(v[1], v[2]); CEH(v[5], v[6]); CEH(v[0], v[4]); CEH(v[3], v[7]);
    CEH(v[1], v[5]); CEH(v[2], v[6]);
    CEH(v[1], v[4]); CEH(v[3], v[6]);
    CEH(v[2], v[4]); CEH(v[3], v[5]);
    CEH(v[3], v[4]);
}
__device__ __forceinline__ void sort4_h2(h2* v) {
    CEH(v[0], v[1]); CEH(v[2], v[3]); CEH(v[0], v[2]); CEH(v[1], v[3]); CEH(v[1], v[2]);
}

// ---------------- K0: pack per-(c,i) weights as fp16 {w,w} u32 pairs ----------------
// wtab[(c*4+i)*16 + j]: j0..2 = l1w[0..2], j3 = 2*l1w[3], j4 = l1b,
//                       j5..12 = l2w[0..7], j13 = l2b.  wtab[1024 + c*4 + k] = bw.
__global__ __launch_bounds__(256) void k_pack(const float* __restrict__ l1w,
                                              const float* __restrict__ l1b,
                                              const float* __restrict__ l2w,
                                              const float* __restrict__ l2b,
                                              const float* __restrict__ bw,
                                              unsigned* __restrict__ wtab) {
    for (int t = threadIdx.x; t < 1088; t += 256) {
        float v = 0.f;
        if (t < 1024) {
            int c = t >> 6, i = (t >> 4) & 3, j = t & 15;
            if (j < 3)        v = l1w[i * 64 + c * 4 + j];
            else if (j == 3)  v = 2.f * l1w[i * 64 + c * 4 + 3];
            else if (j == 4)  v = l1b[i * 16 + c];
            else if (j < 13)  v = l2w[i * 128 + c * 8 + (j - 5)];
            else if (j == 13) v = l2b[i * 16 + c];
        } else {
            v = bw[t - 1024];
        }
        unsigned hs = (unsigned)__half_as_ushort(__float2half(v));
        wtab[t] = hs * 0x10001u;
    }
}

// ---------------- K1: in_conv 1x1, 64 -> 16, 4-px float4, LDS weights, fp16 out ----------------
__global__ __launch_bounds__(256, 4) void k_inconv(const float* __restrict__ cen,
                                                   const float* __restrict__ w,
                                                   const float* __restrict__ bias,
                                                   __half* __restrict__ xh) {
    __shared__ float wl[1040];   // wl[i*16+o] = w[o*64+i], + bias at 1024
    int tid = threadIdx.x;
    for (int t = tid; t < 1024; t += 256) wl[t] = w[(t & 15) * 64 + (t >> 4)];
    if (tid < 16) wl[1024 + tid] = bias[tid];
    __syncthreads();

    int q  = blockIdx.x * 256 + tid;      // quad index, 0..131071
    int b_ = q >> 14;                     // 16384 quads per image
    int hw = (q & 16383) * 4;
    const float* src = cen + (size_t)(b_ * 64) * HW + hw;

    float4 acc[16];
#pragma unroll
    for (int o = 0; o < 16; o++) { float bv = wl[1024 + o]; acc[o] = make_float4(bv, bv, bv, bv); }

#pragma unroll 4
    for (int i = 0; i < 64; i++) {
        float4 xv = *(const float4*)(src + (size_t)i * HW);
        const float4* wq = (const float4*)&wl[i * 16];   // uniform -> ds broadcast
#pragma unroll
        for (int g = 0; g < 4; g++) {
            float4 f = wq[g];
            acc[g * 4 + 0].x += xv.x * f.x; acc[g * 4 + 0].y += xv.y * f.x;
            acc[g * 4 + 0].z += xv.z * f.x; acc[g * 4 + 0].w += xv.w * f.x;
            acc[g * 4 + 1].x += xv.x * f.y; acc[g * 4 + 1].y += xv.y * f.y;
            acc[g * 4 + 1].z += xv.z * f.y; acc[g * 4 + 1].w += xv.w * f.y;
            acc[g * 4 + 2].x += xv.x * f.z; acc[g * 4 + 2].y += xv.y * f.z;
            acc[g * 4 + 2].z += xv.z * f.z; acc[g * 4 + 2].w += xv.w * f.z;
            acc[g * 4 + 3].x += xv.x * f.w; acc[g * 4 + 3].y += xv.y * f.w;
            acc[g * 4 + 3].z += xv.z * f.w; acc[g * 4 + 3].w += xv.w * f.w;
        }
    }
    __half* dst = xh + (size_t)(b_ * 16) * HW + hw;
#pragma unroll
    for (int o = 0; o < 16; o++) {
        uint2 pk;
        pk.x = __builtin_bit_cast(unsigned, __floats2half2_rn(acc[o].x, acc[o].y));
        pk.y = __builtin_bit_cast(unsigned, __floats2half2_rn(acc[o].z, acc[o].w));
        *(uint2*)(dst + (size_t)o * HW) = pk;
    }
}

// ---------------- K2: 4 depthwise convs -> zero-guarded padded fp16 planes ----------------
// 34x34 padded-plane tile per block; input halo 3+7 each side.
__global__ __launch_bounds__(256) void k_dw(const __half* __restrict__ xh,
    const float* __restrict__ dw_w1, const float* __restrict__ dw_b1,
    const float* __restrict__ dw_w3, const float* __restrict__ dw_b3,
    const float* __restrict__ dw_w5, const float* __restrict__ dw_b5,
    const float* __restrict__ dw_w7, const float* __restrict__ dw_b7,
    __half* __restrict__ conv) {
    const int plane = blockIdx.y;               // b*16 + c
    const int c     = plane & 15;
    const int P0    = (blockIdx.x >> 3) * 34;   // padded row origin (8x34 = 272)
    const int Q0    = (blockIdx.x & 7) * 34;    // padded col origin
    const int tid   = threadIdx.x;

    __shared__ float lx[40 * 44];               // image rows/cols P0-10..P0+29 (40x42 used)
    const __half* xp = xh + (size_t)plane * HW;

    for (int t = tid; t < 40 * 21; t += 256) {  // 40 rows x 21 dword-pairs
        int r = t / 21, d = t - r * 21;
        int gy = P0 - 10 + r, gx = Q0 - 10 + 2 * d;   // gx even; pairs never straddle [0,256)
        float2 v = make_float2(0.f, 0.f);
        if ((unsigned)gy < 256u && (unsigned)gx < 256u)
            v = __half22float2(*(const __half2*)(xp + gy * 256 + gx));
        lx[r * 44 + 2 * d]     = v.x;
        lx[r * 44 + 2 * d + 1] = v.y;
    }
    __syncthreads();

    const float* W7 = dw_w7 + c * 49;
    const float* W5 = dw_w5 + c * 25;
    const float* W3 = dw_w3 + c * 9;
    const float  W1 = dw_w1[c];
    const float  B1 = dw_b1[c], B3 = dw_b3[c], B5 = dw_b5[c], B7 = dw_b7[c];

    for (int u = tid; u < 34 * 17; u += 256) {  // 34 rows x 17 col-pairs
        int row = u / 17;
        int pc0 = (u - row * 17) * 2;
        v2f c7v = {0, 0}, c5v = {0, 0}, c3v = {0, 0}, c1v = {0, 0};
#pragma unroll
        for (int a = 0; a < 7; a++) {
            const float* rp = &lx[(row + a) * 44 + pc0];
            v2f q0 = *(const v2f*)rp;
            v2f q1 = *(const v2f*)(rp + 2);
            v2f q2 = *(const v2f*)(rp + 4);
            v2f q3 = *(const v2f*)(rp + 6);
            float v8 = rp[8];
            float v[9] = {q0.x, q0.y, q1.x, q1.y, q2.x, q2.y, q3.x, q3.y, v8};
#pragma unroll
            for (int bb = 0; bb < 7; bb++) {
                v2f vv = {v[bb], v[bb + 1]};
                c7v += vv * W7[a * 7 + bb];
            }
            if (a >= 1 && a <= 5) {
#pragma unroll
                for (int bb = 0; bb < 5; bb++) {
                    v2f vv = {v[bb + 1], v[bb + 2]};
                    c5v += vv * W5[(a - 1) * 5 + bb];
                }
            }
            if (a >= 2 && a <= 4) {
#pragma unroll
                for (int bb = 0; bb < 3; bb++) {
                    v2f vv = {v[bb + 2], v[bb + 3]};
                    c3v += vv * W3[(a - 2) * 3 + bb];
                }
            }
            if (a == 3) {
                v2f vv = {v[3], v[4]};
                c1v = vv * W1;
            }
        }
        int py = P0 + row, px = Q0 + pc0;
        int iy = py - 7, ix = px - 7;
        bool rin = (unsigned)iy < 256u;
        bool in0 = rin && (unsigned)ix < 256u;
        bool in1 = rin && (unsigned)(ix + 1) < 256u;
        size_t o = (size_t)(plane * 4) * PLANE + (size_t)py * PITCH + px;
        *(__half2*)&conv[o]             = __floats2half2_rn(in0 ? c1v.x + B1 : 0.f, in1 ? c1v.y + B1 : 0.f);
        *(__half2*)&conv[o + PLANE]     = __floats2half2_rn(in0 ? c3v.x + B3 : 0.f, in1 ? c3v.y + B3 : 0.f);
        *(__half2*)&conv[o + 2 * PLANE] = __floats2half2_rn(in0 ? c5v.x + B5 : 0.f, in1 ? c5v.y + B5 : 0.f);
        *(__half2*)&conv[o + 3 * PLANE] = __floats2half2_rn(in0 ? c7v.x + B7 : 0.f, in1 ? c7v.y + B7 : 0.f);
    }
}

// ---------------- K3: machinery, LDS-staged conv tiles, all-fp16, fused tail ----------------
// block = 32x32 image tile, 512 threads = 512 pixel-pairs (1 pair/thread).
// Per c: stage 4 plane tiles (46 rows x 24 dwords each) into LDS, then compute.
__global__ __launch_bounds__(512, 4) void k_mach(const __half* __restrict__ conv,
                                                 const unsigned* __restrict__ wtab,
                                                 const float* __restrict__ bns,
                                                 const float* __restrict__ bnb,
                                                 const float* __restrict__ fw,
                                                 const float* __restrict__ fb,
                                                 float* __restrict__ out) {
    const int b_  = blockIdx.y;                  // 0..7
    const int ty0 = (blockIdx.x >> 3) * 32;      // tile origin (image coords)
    const int tx0 = (blockIdx.x & 7) * 32;
    const int tid = threadIdx.x;
    const int py  = tid >> 4;                    // 0..31
    const int pxp = tid & 15;                    // pair within row

    __shared__ __align__(16) unsigned convt[4 * 46 * 24];   // 4 planes x 46 rows x 24 dwords

    float fyx = fb[0], fyy = fb[0];

    for (int c = 0; c < 16; c++) {
        if (c) __syncthreads();
        // ---- stage: 4 planes x 46 rows x 12 uint2 = 2208 8B units ----
        {
            const size_t pb4 = (size_t)(b_ * 64 + c * 4) * PLANE;
#pragma unroll
            for (int j = 0; j < 5; j++) {
                int t = tid + j * 512;
                if (t < 2208) {
                    int i  = t / 552;
                    int rm = t - i * 552;
                    int r  = rm / 12;
                    int d2 = rm - r * 12;
                    size_t E = pb4 + (size_t)i * PLANE + (size_t)(ty0 + r) * PITCH + tx0 + 4 * d2;
                    ((uint2*)convt)[t] = *(const uint2*)(conv + E);   // 8B aligned
                }
            }
        }
        __syncthreads();

        h2 bh[4];
#pragma unroll
        for (int i = 0; i < 4; i++) {
            const int s = 1 + 2 * i;
            const unsigned* pl = convt + i * 1104;
            const int q    = pxp + (7 - s) / 2;          // start dword within row
            const int topb = (py + 7 - s) * 24 + q;
            const int midb = (py + 7) * 24 + q;
            const int botb = (py + 7 + s) * 24 + q;

            unsigned tt[8], tm[8], tb[8];
#pragma unroll
            for (int k = 0; k <= s; k++) {
                tt[k] = pl[topb + k];
                tm[k] = pl[midb + k];
                tb[k] = pl[botb + k];
            }
            const int m = s >> 1;   // (s-1)/2
            h2 n0  = uh(tt[0]);
            h2 n1  = uh((tt[m] >> 16) | (tt[m + 1] << 16));
            h2 n2  = uh(tt[s]);
            h2 n7  = uh(tm[0]);
            h2 ctr = uh((tm[m] >> 16) | (tm[m + 1] << 16));
            h2 n3  = uh(tm[s]);
            h2 n6  = uh(tb[0]);
            h2 n5  = uh((tb[m] >> 16) | (tb[m + 1] << 16));
            h2 n4  = uh(tb[s]);

            h2 T[8];
            T[0] = ctr - n0; T[1] = ctr - n1; T[2] = ctr - n2; T[3] = ctr - n3;
            T[4] = ctr - n4; T[5] = ctr - n5; T[6] = ctr - n6; T[7] = ctr - n7;
            h2 S[4];
#pragma unroll
            for (int k = 0; k < 4; k++) S[k] = T[k] + T[k + 4];

            const unsigned* wt = wtab + ((c << 2) + i) * 16;   // uniform -> s_load
            h2 w10 = uh(wt[0]), w11 = uh(wt[1]), w12 = uh(wt[2]);
            h2 w13x2 = uh(wt[3]), bb1 = uh(wt[4]);

            h2 R[4];
#pragma unroll
            for (int mm = 0; mm < 4; mm++) {
                h2 r = S[(mm + 2) & 3] * w12 + bb1;
                r = S[(mm + 3) & 3] * w11 + r;
                r = S[(mm + 1) & 3] * w10 + r;
                R[mm] = r;
            }
            h2 h8[8];
#pragma unroll
            for (int k = 0; k < 8; k++)
                h8[k] = (T[(k + 4) & 7] * w13x2 + R[k & 3]) * T[k];
            sort8_h2(h8);

            h2 acc = uh(wt[13]);
#pragma unroll
            for (int k = 0; k < 8; k++) acc += h8[k] * uh(wt[5 + k]);
            bh[i] = acc;
        }
        sort4_h2(bh);
        h2 yv = bh[0] * uh(wtab[1024 + (c << 2)]);
#pragma unroll
        for (int k = 1; k < 4; k++) yv = bh[k] * uh(wtab[1024 + (c << 2) + k]) + yv;

        float zx = fmaf((float)yv.x, bns[c], bnb[c]);
        float zy = fmaf((float)yv.y, bns[c], bnb[c]);
        float sx = zx / (1.f + __expf(-zx));
        float sy = zy / (1.f + __expf(-zy));
        fyx = fmaf(sx, fw[c], fyx);
        fyy = fmaf(sy, fw[c], fyy);
    }
    float2 r;
    r.x = 1.f / (1.f + __expf(-fyx));
    r.y = 1.f / (1.f + __expf(-fyy));
    *(float2*)&out[((long)b_ << 16) + (ty0 + py) * 256 + tx0 + 2 * pxp] = r;
}

extern "C" void kernel_launch(void* const* d_in, const int* in_sizes, int n_in,
                              void* d_out, int out_size, void* d_ws, size_t ws_size,
                              hipStream_t stream) {
    (void)in_sizes; (void)n_in; (void)out_size; (void)ws_size;
    const float* cen   = (const float*)d_in[0];
    // d_in[1] = mas (unused by the reference)
    const float* in_w  = (const float*)d_in[2];
    const float* in_b  = (const float*)d_in[3];
    const float* dw_w1 = (const float*)d_in[4];
    const float* dw_b1 = (const float*)d_in[5];
    const float* dw_w3 = (const float*)d_in[6];
    const float* dw_b3 = (const float*)d_in[7];
    const float* dw_w5 = (const float*)d_in[8];
    const float* dw_b5 = (const float*)d_in[9];
    const float* dw_w7 = (const float*)d_in[10];
    const float* dw_b7 = (const float*)d_in[11];
    const float* l1w   = (const float*)d_in[12];
    const float* l1b   = (const float*)d_in[13];
    const float* l2w   = (const float*)d_in[14];
    const float* l2b   = (const float*)d_in[15];
    const float* bw    = (const float*)d_in[16];
    const float* bns   = (const float*)d_in[17];
    const float* bnb   = (const float*)d_in[18];
    const float* fw    = (const float*)d_in[19];
    const float* fb    = (const float*)d_in[20];

    // workspace: xh (16.78 MB) | conv (75.76 MB) | wtab (4.3 KB)
    __half*   xh   = (__half*)d_ws;
    __half*   conv = (__half*)((char*)d_ws + (size_t)16777216);
    unsigned* wtab = (unsigned*)((char*)d_ws + (size_t)16777216 + (size_t)75759616);
    float*    out  = (float*)d_out;

    k_pack<<<1, 256, 0, stream>>>(l1w, l1b, l2w, l2b, bw, wtab);
    k_inconv<<<512, 256, 0, stream>>>(cen, in_w, in_b, xh);
    k_dw<<<dim3(64, 128), 256, 0, stream>>>(xh, dw_w1, dw_b1, dw_w3, dw_b3,
                                            dw_w5, dw_b5, dw_w7, dw_b7, conv);
    k_mach<<<dim3(64, 8), 512, 0, stream>>>(conv, wtab, bns, bnb, fw, fb, out);
}

// Round 3
// 364.838 us; speedup vs baseline: 1.0095x; 1.0095x over previous
//
#include <hip/hip_runtime.h>
#include <hip/hip_fp16.h>
#include <math.h>

#define HW 65536               // 256*256
#define PITCH 272              // padded fp16 conv plane: 7+256+9 cols
#define PLANE (PITCH * PITCH)  // 73984 fp16 elements per (b,c,i) plane

typedef float v2f __attribute__((ext_vector_type(2), aligned(8)));
typedef _Float16 h2 __attribute__((ext_vector_type(2)));

__device__ __forceinline__ h2 uh(unsigned u) { return __builtin_bit_cast(h2, u); }

#define CEH(a, b) { h2 _t = __builtin_elementwise_min(a, b); \
                    b = __builtin_elementwise_max(a, b); a = _t; }

__device__ __forceinline__ void sort8_h2(h2* v) {
    CEH(v[0], v[1]); CEH(v[2], v[3]); CEH(v[4], v[5]); CEH(v[6], v[7]);
    CEH(v[0], v[2]); CEH(v[1], v[3]); CEH(v[4], v[6]); CEH(v[5], v[7]);
    CEH(v[1], v[2]); CEH(v[5], v[6]); CEH(v[0], v[4]); CEH(v[3], v[7]);
    CEH(v[1], v[5]); CEH(v[2], v[6]);
    CEH(v[1], v[4]); CEH(v[3], v[6]);
    CEH(v[2], v[4]); CEH(v[3], v[5]);
    CEH(v[3], v[4]);
}
__device__ __forceinline__ void sort4_h2(h2* v) {
    CEH(v[0], v[1]); CEH(v[2], v[3]); CEH(v[0], v[2]); CEH(v[1], v[3]); CEH(v[1], v[2]);
}

// ---------------- K0: pack per-(c,i) weights as fp16 {w,w} u32 pairs ----------------
// wtab[(c*4+i)*16 + j]: j0..2 = l1w[0..2], j3 = 2*l1w[3], j4 = l1b,
//                       j5..12 = l2w[0..7], j13 = l2b.  wtab[1024 + c*4 + k] = bw.
__global__ __launch_bounds__(256) void k_pack(const float* __restrict__ l1w,
                                              const float* __restrict__ l1b,
                                              const float* __restrict__ l2w,
                                              const float* __restrict__ l2b,
                                              const float* __restrict__ bw,
                                              unsigned* __restrict__ wtab) {
    for (int t = threadIdx.x; t < 1088; t += 256) {
        float v = 0.f;
        if (t < 1024) {
            int c = t >> 6, i = (t >> 4) & 3, j = t & 15;
            if (j < 3)        v = l1w[i * 64 + c * 4 + j];
            else if (j == 3)  v = 2.f * l1w[i * 64 + c * 4 + 3];
            else if (j == 4)  v = l1b[i * 16 + c];
            else if (j < 13)  v = l2w[i * 128 + c * 8 + (j - 5)];
            else if (j == 13) v = l2b[i * 16 + c];
        } else {
            v = bw[t - 1024];
        }
        unsigned hs = (unsigned)__half_as_ushort(__float2half(v));
        wtab[t] = hs * 0x10001u;
    }
}

// ---------------- K1: in_conv 1x1, 64 -> 16, 4-px float4, LDS weights, fp16 out ----------------
__global__ __launch_bounds__(256, 4) void k_inconv(const float* __restrict__ cen,
                                                   const float* __restrict__ w,
                                                   const float* __restrict__ bias,
                                                   __half* __restrict__ xh) {
    __shared__ float wl[1040];   // wl[i*16+o] = w[o*64+i], + bias at 1024
    int tid = threadIdx.x;
    for (int t = tid; t < 1024; t += 256) wl[t] = w[(t & 15) * 64 + (t >> 4)];
    if (tid < 16) wl[1024 + tid] = bias[tid];
    __syncthreads();

    int q  = blockIdx.x * 256 + tid;      // quad index, 0..131071
    int b_ = q >> 14;                     // 16384 quads per image
    int hw = (q & 16383) * 4;
    const float* src = cen + (size_t)(b_ * 64) * HW + hw;

    float4 acc[16];
#pragma unroll
    for (int o = 0; o < 16; o++) { float bv = wl[1024 + o]; acc[o] = make_float4(bv, bv, bv, bv); }

#pragma unroll 4
    for (int i = 0; i < 64; i++) {
        float4 xv = *(const float4*)(src + (size_t)i * HW);
        const float4* wq = (const float4*)&wl[i * 16];   // uniform -> ds broadcast
#pragma unroll
        for (int g = 0; g < 4; g++) {
            float4 f = wq[g];
            acc[g * 4 + 0].x += xv.x * f.x; acc[g * 4 + 0].y += xv.y * f.x;
            acc[g * 4 + 0].z += xv.z * f.x; acc[g * 4 + 0].w += xv.w * f.x;
            acc[g * 4 + 1].x += xv.x * f.y; acc[g * 4 + 1].y += xv.y * f.y;
            acc[g * 4 + 1].z += xv.z * f.y; acc[g * 4 + 1].w += xv.w * f.y;
            acc[g * 4 + 2].x += xv.x * f.z; acc[g * 4 + 2].y += xv.y * f.z;
            acc[g * 4 + 2].z += xv.z * f.z; acc[g * 4 + 2].w += xv.w * f.z;
            acc[g * 4 + 3].x += xv.x * f.w; acc[g * 4 + 3].y += xv.y * f.w;
            acc[g * 4 + 3].z += xv.z * f.w; acc[g * 4 + 3].w += xv.w * f.w;
        }
    }
    __half* dst = xh + (size_t)(b_ * 16) * HW + hw;
#pragma unroll
    for (int o = 0; o < 16; o++) {
        uint2 pk;
        pk.x = __builtin_bit_cast(unsigned, __floats2half2_rn(acc[o].x, acc[o].y));
        pk.y = __builtin_bit_cast(unsigned, __floats2half2_rn(acc[o].z, acc[o].w));
        *(uint2*)(dst + (size_t)o * HW) = pk;
    }
}

// ---------------- K2: 4 depthwise convs -> zero-guarded padded fp16 planes ----------------
// 34x34 padded-plane tile per block; input halo 3+7 each side.
__global__ __launch_bounds__(256) void k_dw(const __half* __restrict__ xh,
    const float* __restrict__ dw_w1, const float* __restrict__ dw_b1,
    const float* __restrict__ dw_w3, const float* __restrict__ dw_b3,
    const float* __restrict__ dw_w5, const float* __restrict__ dw_b5,
    const float* __restrict__ dw_w7, const float* __restrict__ dw_b7,
    __half* __restrict__ conv) {
    const int plane = blockIdx.y;               // b*16 + c
    const int c     = plane & 15;
    const int P0    = (blockIdx.x >> 3) * 34;   // padded row origin (8x34 = 272)
    const int Q0    = (blockIdx.x & 7) * 34;    // padded col origin
    const int tid   = threadIdx.x;

    __shared__ float lx[40 * 44];               // image rows/cols P0-10..P0+29 (40x42 used)
    const __half* xp = xh + (size_t)plane * HW;

    for (int t = tid; t < 40 * 21; t += 256) {  // 40 rows x 21 dword-pairs
        int r = t / 21, d = t - r * 21;
        int gy = P0 - 10 + r, gx = Q0 - 10 + 2 * d;   // gx even; pairs never straddle [0,256)
        float2 v = make_float2(0.f, 0.f);
        if ((unsigned)gy < 256u && (unsigned)gx < 256u)
            v = __half22float2(*(const __half2*)(xp + gy * 256 + gx));
        lx[r * 44 + 2 * d]     = v.x;
        lx[r * 44 + 2 * d + 1] = v.y;
    }
    __syncthreads();

    const float* W7 = dw_w7 + c * 49;
    const float* W5 = dw_w5 + c * 25;
    const float* W3 = dw_w3 + c * 9;
    const float  W1 = dw_w1[c];
    const float  B1 = dw_b1[c], B3 = dw_b3[c], B5 = dw_b5[c], B7 = dw_b7[c];

    for (int u = tid; u < 34 * 17; u += 256) {  // 34 rows x 17 col-pairs
        int row = u / 17;
        int pc0 = (u - row * 17) * 2;
        v2f c7v = {0, 0}, c5v = {0, 0}, c3v = {0, 0}, c1v = {0, 0};
#pragma unroll
        for (int a = 0; a < 7; a++) {
            const float* rp = &lx[(row + a) * 44 + pc0];
            v2f q0 = *(const v2f*)rp;
            v2f q1 = *(const v2f*)(rp + 2);
            v2f q2 = *(const v2f*)(rp + 4);
            v2f q3 = *(const v2f*)(rp + 6);
            float v8 = rp[8];
            float v[9] = {q0.x, q0.y, q1.x, q1.y, q2.x, q2.y, q3.x, q3.y, v8};
#pragma unroll
            for (int bb = 0; bb < 7; bb++) {
                v2f vv = {v[bb], v[bb + 1]};
                c7v += vv * W7[a * 7 + bb];
            }
            if (a >= 1 && a <= 5) {
#pragma unroll
                for (int bb = 0; bb < 5; bb++) {
                    v2f vv = {v[bb + 1], v[bb + 2]};
                    c5v += vv * W5[(a - 1) * 5 + bb];
                }
            }
            if (a >= 2 && a <= 4) {
#pragma unroll
                for (int bb = 0; bb < 3; bb++) {
                    v2f vv = {v[bb + 2], v[bb + 3]};
                    c3v += vv * W3[(a - 2) * 3 + bb];
                }
            }
            if (a == 3) {
                v2f vv = {v[3], v[4]};
                c1v = vv * W1;
            }
        }
        int py = P0 + row, px = Q0 + pc0;
        int iy = py - 7, ix = px - 7;
        bool rin = (unsigned)iy < 256u;
        bool in0 = rin && (unsigned)ix < 256u;
        bool in1 = rin && (unsigned)(ix + 1) < 256u;
        size_t o = (size_t)(plane * 4) * PLANE + (size_t)py * PITCH + px;
        *(__half2*)&conv[o]             = __floats2half2_rn(in0 ? c1v.x + B1 : 0.f, in1 ? c1v.y + B1 : 0.f);
        *(__half2*)&conv[o + PLANE]     = __floats2half2_rn(in0 ? c3v.x + B3 : 0.f, in1 ? c3v.y + B3 : 0.f);
        *(__half2*)&conv[o + 2 * PLANE] = __floats2half2_rn(in0 ? c5v.x + B5 : 0.f, in1 ? c5v.y + B5 : 0.f);
        *(__half2*)&conv[o + 3 * PLANE] = __floats2half2_rn(in0 ? c7v.x + B7 : 0.f, in1 ? c7v.y + B7 : 0.f);
    }
}

// ---------------- K3: machinery, one (32x32 tile, c) per block, fp16, silu out ----------------
// grid (64, 128): x = tile (8x8), y = b*16 + c.  512 threads = 512 pixel-pairs.
__global__ __launch_bounds__(512, 4) void k_mach(const __half* __restrict__ conv,
                                                 const unsigned* __restrict__ wtab,
                                                 const float* __restrict__ bns,
                                                 const float* __restrict__ bnb,
                                                 __half* __restrict__ y16) {
    const int by  = blockIdx.y;                  // b*16 + c
    const int c   = by & 15;
    const int ty0 = (blockIdx.x >> 3) * 32;      // tile origin (image coords)
    const int tx0 = (blockIdx.x & 7) * 32;
    const int tid = threadIdx.x;
    const int py  = tid >> 4;                    // 0..31
    const int pxp = tid & 15;                    // pair within row

    __shared__ __align__(16) unsigned convt[4 * 46 * 24];   // 4 planes x 46 rows x 24 dwords

    // ---- stage: 4 planes x 46 rows x 6 uint4 = 1104 16B units ----
    {
        const size_t pb4 = (size_t)(by * 4) * PLANE;
#pragma unroll
        for (int j = 0; j < 3; j++) {
            int t = tid + j * 512;
            if (t < 1104) {
                int i  = t / 276;
                int rm = t - i * 276;
                int r  = rm / 6;
                int d4 = rm - r * 6;
                size_t E = pb4 + (size_t)i * PLANE + (size_t)(ty0 + r) * PITCH + tx0 + 8 * d4;
                ((uint4*)convt)[t] = *(const uint4*)(conv + E);   // 16B aligned
            }
        }
    }
    __syncthreads();

    h2 bh[4];
#pragma unroll
    for (int i = 0; i < 4; i++) {
        const int s = 1 + 2 * i;
        const unsigned* pl = convt + i * 1104;
        const int q    = pxp + (7 - s) / 2;          // start dword within row
        const int topb = (py + 7 - s) * 24 + q;
        const int midb = (py + 7) * 24 + q;
        const int botb = (py + 7 + s) * 24 + q;

        unsigned tt[8], tm[8], tb[8];
#pragma unroll
        for (int k = 0; k <= s; k++) {
            tt[k] = pl[topb + k];
            tm[k] = pl[midb + k];
            tb[k] = pl[botb + k];
        }
        const int m = s >> 1;   // (s-1)/2
        h2 n0  = uh(tt[0]);
        h2 n1  = uh((tt[m] >> 16) | (tt[m + 1] << 16));
        h2 n2  = uh(tt[s]);
        h2 n7  = uh(tm[0]);
        h2 ctr = uh((tm[m] >> 16) | (tm[m + 1] << 16));
        h2 n3  = uh(tm[s]);
        h2 n6  = uh(tb[0]);
        h2 n5  = uh((tb[m] >> 16) | (tb[m + 1] << 16));
        h2 n4  = uh(tb[s]);

        h2 T[8];
        T[0] = ctr - n0; T[1] = ctr - n1; T[2] = ctr - n2; T[3] = ctr - n3;
        T[4] = ctr - n4; T[5] = ctr - n5; T[6] = ctr - n6; T[7] = ctr - n7;
        h2 S[4];
#pragma unroll
        for (int k = 0; k < 4; k++) S[k] = T[k] + T[k + 4];

        const unsigned* wt = wtab + ((c << 2) + i) * 16;   // block-uniform -> s_load
        h2 w10 = uh(wt[0]), w11 = uh(wt[1]), w12 = uh(wt[2]);
        h2 w13x2 = uh(wt[3]), bb1 = uh(wt[4]);

        h2 R[4];
#pragma unroll
        for (int mm = 0; mm < 4; mm++) {
            h2 r = S[(mm + 2) & 3] * w12 + bb1;
            r = S[(mm + 3) & 3] * w11 + r;
            r = S[(mm + 1) & 3] * w10 + r;
            R[mm] = r;
        }
        h2 h8[8];
#pragma unroll
        for (int k = 0; k < 8; k++)
            h8[k] = (T[(k + 4) & 7] * w13x2 + R[k & 3]) * T[k];
        sort8_h2(h8);

        h2 acc = uh(wt[13]);
#pragma unroll
        for (int k = 0; k < 8; k++) acc += h8[k] * uh(wt[5 + k]);
        bh[i] = acc;
    }
    sort4_h2(bh);
    h2 yv = bh[0] * uh(wtab[1024 + (c << 2)]);
#pragma unroll
    for (int k = 1; k < 4; k++) yv = bh[k] * uh(wtab[1024 + (c << 2) + k]) + yv;

    const float bsc = bns[c], bbi = bnb[c];      // block-uniform -> s_load
    float zx = fmaf((float)yv.x, bsc, bbi);
    float zy = fmaf((float)yv.y, bsc, bbi);
    float sx = zx / (1.f + __expf(-zx));
    float sy = zy / (1.f + __expf(-zy));
    *(__half2*)&y16[(size_t)by * HW + (ty0 + py) * 256 + tx0 + 2 * pxp] =
        __floats2half2_rn(sx, sy);
}

// ---------------- K4: final 1x1 16 -> 1 + sigmoid ----------------
__global__ __launch_bounds__(256) void k_final(const __half* __restrict__ y16,
                                               const float* __restrict__ fw,
                                               const float* __restrict__ fb,
                                               float* __restrict__ out) {
    long t  = (long)blockIdx.x * 256 + threadIdx.x;   // pair index
    long p0 = t * 2;
    int  b  = (int)(p0 >> 16);
    int  hw = (int)(p0 & 65535);

    float accx = fb[0], accy = fb[0];
#pragma unroll
    for (int cc = 0; cc < 16; cc++) {
        __half2 h = *(const __half2*)(y16 + (size_t)(b * 16 + cc) * HW + hw);
        float2 v = __half22float2(h);
        float wv = fw[cc];
        accx = fmaf(v.x, wv, accx);
        accy = fmaf(v.y, wv, accy);
    }
    float2 r;
    r.x = 1.f / (1.f + __expf(-accx));
    r.y = 1.f / (1.f + __expf(-accy));
    *(float2*)(out + p0) = r;
}

extern "C" void kernel_launch(void* const* d_in, const int* in_sizes, int n_in,
                              void* d_out, int out_size, void* d_ws, size_t ws_size,
                              hipStream_t stream) {
    (void)in_sizes; (void)n_in; (void)out_size; (void)ws_size;
    const float* cen   = (const float*)d_in[0];
    // d_in[1] = mas (unused by the reference)
    const float* in_w  = (const float*)d_in[2];
    const float* in_b  = (const float*)d_in[3];
    const float* dw_w1 = (const float*)d_in[4];
    const float* dw_b1 = (const float*)d_in[5];
    const float* dw_w3 = (const float*)d_in[6];
    const float* dw_b3 = (const float*)d_in[7];
    const float* dw_w5 = (const float*)d_in[8];
    const float* dw_b5 = (const float*)d_in[9];
    const float* dw_w7 = (const float*)d_in[10];
    const float* dw_b7 = (const float*)d_in[11];
    const float* l1w   = (const float*)d_in[12];
    const float* l1b   = (const float*)d_in[13];
    const float* l2w   = (const float*)d_in[14];
    const float* l2b   = (const float*)d_in[15];
    const float* bw    = (const float*)d_in[16];
    const float* bns   = (const float*)d_in[17];
    const float* bnb   = (const float*)d_in[18];
    const float* fw    = (const float*)d_in[19];
    const float* fb    = (const float*)d_in[20];

    // workspace: xh (16.78 MB) | conv (75.76 MB) | wtab (8 KB) | y16 (16.78 MB)
    __half*   xh   = (__half*)d_ws;
    __half*   conv = (__half*)((char*)d_ws + (size_t)16777216);
    unsigned* wtab = (unsigned*)((char*)d_ws + (size_t)16777216 + (size_t)75759616);
    __half*   y16  = (__half*)((char*)d_ws + (size_t)16777216 + (size_t)75759616 + 8192);
    float*    out  = (float*)d_out;

    k_pack<<<1, 256, 0, stream>>>(l1w, l1b, l2w, l2b, bw, wtab);
    k_inconv<<<512, 256, 0, stream>>>(cen, in_w, in_b, xh);
    k_dw<<<dim3(64, 128), 256, 0, stream>>>(xh, dw_w1, dw_b1, dw_w3, dw_b3,
                                            dw_w5, dw_b5, dw_w7, dw_b7, conv);
    k_mach<<<dim3(64, 128), 512, 0, stream>>>(conv, wtab, bns, bnb, y16);
    k_final<<<1024, 256, 0, stream>>>(y16, fw, fb, out);
}